// Round 3
// baseline (173.329 us; speedup 1.0000x reference)
//
#include <hip/hip_runtime.h>
#include <math.h>

// Problem constants (fixed by the reference setup_inputs): B=2, P=8192, K=16
#define PP    8192
#define NB    2
#define NPTS  16384          // NB * PP
#define KNN   16
#define EPSV  1e-17f
#define CH    128            // chunks of 64 sorted points per batch
#define NCELL 4096           // 12-bit Morton (4 bits/axis)

#define QPB   64
#define WPB   8
#define TPB   (WPB * 64)     // 512

#define KEY_BIG 3.0e38f      // > any real key, finite

// ---------------------------------------------------------------------------
// Sorted-order exact KNN:
//  S1 zero hist | S2 morton hist | S3 scan->cursors | S4 scatter | S5 bboxes
//  K1 per-chunk KNN with exact bbox skipping + fused phi/n1 tail
// Invariant (bug fixed vs R2): every candidate is examined by EXACTLY ONE
// wave (own chunk folded into the strided enumeration at t=0), so the 8
// per-wave partial top-16 lists are DISJOINT and the multiset merge16 cannot
// duplicate a neighbor. Self is excluded inside process_chunk (j == own).
// Skip-exactness: a chunk is skipped only if pack_floor(min_dist^2 to bbox)
// >= keys[15] for all lanes; every candidate key in the chunk >= that floor,
// keys only shrink, merged-16th <= any wave's 16th, keys injective (index
// bits) -> no final-set member can be skipped. A wave's first processed
// chunk is never skipped (keys[15]==KEY_BIG), so skips always compare
// against 16 real keys.
// ---------------------------------------------------------------------------

__device__ __forceinline__ int spread3(int v) {   // 4-bit v -> bits 0,3,6,9
    return (v & 1) | ((v & 2) << 2) | ((v & 4) << 4) | ((v & 8) << 6);
}

__global__ void zero_kernel(int* __restrict__ hist) {
#pragma unroll
    for (int k = 0; k < 8; ++k) hist[threadIdx.x + k * 1024] = 0;
}

__global__ void hist_kernel(const float* __restrict__ pts,
                            int* __restrict__ hist) {
    const int p = blockIdx.x * blockDim.x + threadIdx.x;   // 0..16383
    const float x = pts[p * 3 + 0];
    const float y = pts[p * 3 + 1];
    const float z = pts[p * 3 + 2];
    const int ix = (int)fminf(fmaxf((x + 5.0f) * 1.6f, 0.0f), 15.0f);
    const int iy = (int)fminf(fmaxf((y + 5.0f) * 1.6f, 0.0f), 15.0f);
    const int iz = (int)fminf(fmaxf((z + 5.0f) * 1.6f, 0.0f), 15.0f);
    const int c = spread3(ix) | (spread3(iy) << 1) | (spread3(iz) << 2);
    atomicAdd(&hist[(p >> 13) * NCELL + c], 1);
}

__global__ void scan_kernel(const int* __restrict__ hist,
                            int* __restrict__ cursor) {
    // one block per batch, 1024 threads, 4 bins/thread
    const int b = blockIdx.x;
    const int t = threadIdx.x;
    const int base = b * NCELL;
    const int v0 = hist[base + t * 4 + 0];
    const int v1 = hist[base + t * 4 + 1];
    const int v2 = hist[base + t * 4 + 2];
    const int v3 = hist[base + t * 4 + 3];
    const int s4 = v0 + v1 + v2 + v3;
    const int lane = t & 63, wid = t >> 6;
    int v = s4;
#pragma unroll
    for (int off = 1; off < 64; off <<= 1) {
        int u = __shfl_up(v, off, 64);
        if (lane >= off) v += u;
    }
    __shared__ int wtot[16];
    if (lane == 63) wtot[wid] = v;
    __syncthreads();
    if (wid == 0) {
        int w = (lane < 16) ? wtot[lane] : 0;
#pragma unroll
        for (int off = 1; off < 16; off <<= 1) {
            int u = __shfl_up(w, off, 64);
            if (lane >= off) w += u;
        }
        if (lane < 16) wtot[lane] = w;          // inclusive wave totals
    }
    __syncthreads();
    const int wbase = (wid > 0) ? wtot[wid - 1] : 0;
    const int excl = wbase + v - s4;            // exclusive prefix, this thread
    const int o0 = b * PP + excl;
    cursor[base + t * 4 + 0] = o0;
    cursor[base + t * 4 + 1] = o0 + v0;
    cursor[base + t * 4 + 2] = o0 + v0 + v1;
    cursor[base + t * 4 + 3] = o0 + v0 + v1 + v2;
}

__global__ void scatter_kernel(const float* __restrict__ pts,
                               int* __restrict__ cursor,
                               float4* __restrict__ sorted4,
                               int* __restrict__ perm) {
    const int p = blockIdx.x * blockDim.x + threadIdx.x;
    const float x = pts[p * 3 + 0];
    const float y = pts[p * 3 + 1];
    const float z = pts[p * 3 + 2];
    const int ix = (int)fminf(fmaxf((x + 5.0f) * 1.6f, 0.0f), 15.0f);
    const int iy = (int)fminf(fmaxf((y + 5.0f) * 1.6f, 0.0f), 15.0f);
    const int iz = (int)fminf(fmaxf((z + 5.0f) * 1.6f, 0.0f), 15.0f);
    const int c = spread3(ix) | (spread3(iy) << 1) | (spread3(iz) << 2);
    const int pos = atomicAdd(&cursor[(p >> 13) * NCELL + c], 1);
    sorted4[pos] = make_float4(x, y, z, x * x + y * y + z * z);
    perm[pos] = p & (PP - 1);
}

__global__ void bbox_kernel(const float4* __restrict__ sorted4,
                            float4* __restrict__ bbmin,
                            float4* __restrict__ bbmax) {
    const int lane = threadIdx.x & 63;
    const int wave = threadIdx.x >> 6;
    const int cw = blockIdx.x * 8 + wave;       // 0..255 (abs chunk)
    const float4 v = sorted4[cw * 64 + lane];
    float mnx = v.x, mny = v.y, mnz = v.z;
    float mxx = v.x, mxy = v.y, mxz = v.z;
#pragma unroll
    for (int off = 32; off >= 1; off >>= 1) {
        mnx = fminf(mnx, __shfl_xor(mnx, off, 64));
        mny = fminf(mny, __shfl_xor(mny, off, 64));
        mnz = fminf(mnz, __shfl_xor(mnz, off, 64));
        mxx = fmaxf(mxx, __shfl_xor(mxx, off, 64));
        mxy = fmaxf(mxy, __shfl_xor(mxy, off, 64));
        mxz = fmaxf(mxz, __shfl_xor(mxz, off, 64));
    }
    if (lane == 0) {
        bbmin[cw] = make_float4(mnx, mny, mnz, 0.f);
        bbmax[cw] = make_float4(mxx, mxy, mxz, 0.f);
    }
}

__device__ __forceinline__ void insert16(float (&keys)[KNN], float kk) {
#pragma unroll
    for (int s = KNN - 1; s >= 1; --s)
        keys[s] = __builtin_amdgcn_fmed3f(keys[s - 1], kk, keys[s]);
    keys[0] = fminf(keys[0], kk);
}

// Merge two ascending sorted-16 lists, keep lowest 16, result ascending.
__device__ __forceinline__ void merge16(float (&a)[KNN], const float (&o)[KNN]) {
    float c[KNN];
#pragma unroll
    for (int s = 0; s < KNN; ++s) c[s] = fminf(a[s], o[KNN - 1 - s]);
#pragma unroll
    for (int st = KNN / 2; st >= 1; st >>= 1) {
#pragma unroll
        for (int base = 0; base < KNN; base += 2 * st) {
#pragma unroll
            for (int k = 0; k < st; ++k) {
                const float x = c[base + k], y = c[base + k + st];
                c[base + k]      = fminf(x, y);
                c[base + k + st] = fmaxf(x, y);
            }
        }
    }
#pragma unroll
    for (int s = 0; s < KNN; ++s) a[s] = c[s];
}

__global__ __launch_bounds__(TPB, 2) void knn_sorted_kernel(
        const float4* __restrict__ sorted4,
        const int*    __restrict__ perm,
        const float*  __restrict__ normals,
        const float4* __restrict__ bbmin,
        const float4* __restrict__ bbmax,
        int*   __restrict__ out_idx,
        float* __restrict__ out_dist,
        float* __restrict__ out_phi,
        float* __restrict__ out_n1) {
    __shared__ float4 cbuf[WPB][64];              // 8 KB (per-wave staging)
    __shared__ float  smerge[WPB * KNN * 64];     // 32 KB

    const int lane = threadIdx.x & 63;
    const int wave = threadIdx.x >> 6;
    const int g  = blockIdx.x;                    // abs chunk == query group
    const int b  = g >> 7;
    const int c0 = g & (CH - 1);
    const float4* sb = sorted4 + (size_t)b * PP;

    const float4 q4 = sb[c0 * 64 + lane];
    const float qx = q4.x, qy = q4.y, qz = q4.z;
    const float d2q = qx * qx + qy * qy + qz * qz;
    const int own = c0 * 64 + lane;               // query's own sorted index

    float keys[KNN];
#pragma unroll
    for (int s = 0; s < KNN; ++s) keys[s] = KEY_BIG;

    // ---- all 128 chunks, near-first, strided across the 8 waves -----------
    // Every chunk -> exactly one wave => wave partial lists are DISJOINT.
    auto process_chunk = [&](int c) {
        const float4 mn = bbmin[b * CH + c];
        const float4 mx = bbmax[b * CH + c];
        float ddx = fmaxf(fmaxf(mn.x - qx, qx - mx.x), 0.0f);
        float ddy = fmaxf(fmaxf(mn.y - qy, qy - mx.y), 0.0f);
        float ddz = fmaxf(fmaxf(mn.z - qz, qz - mx.z), 0.0f);
        const float dmin2 = (ddx * ddx + ddy * ddy + ddz * ddz) * 0.999999f;
        const float fl = __uint_as_float(__float_as_uint(dmin2) & 0xFFFFE000u);
        if (!__any(fl < keys[KNN - 1])) return;   // exact skip
        cbuf[wave][lane] = sb[c * 64 + lane];
        for (int m0 = 0; m0 < 64; m0 += 4) {
            float4 c4[4];
            float  kk[4];
#pragma unroll
            for (int u = 0; u < 4; ++u) c4[u] = cbuf[wave][m0 + u];
#pragma unroll
            for (int u = 0; u < 4; ++u) {
                const int j = c * 64 + m0 + u;
                const float dot = fmaf(qz, c4[u].z,
                                  fmaf(qy, c4[u].y, qx * c4[u].x));
                const float d  = fmaf(-2.0f, dot, d2q + c4[u].w);
                const float dc = fmaxf(d, 0.0f);
                float kv = __uint_as_float(
                    (__float_as_uint(dc) & 0xFFFFE000u) | (unsigned)j);
                if (j == own) kv = KEY_BIG;       // exclude self
                kk[u] = kv;
            }
#pragma unroll
            for (int u = 0; u < 4; ++u)
                if (__any(kk[u] < keys[KNN - 1])) insert16(keys, kk[u]);
        }
    };

    int t = 0;
    if ((t & 7) == wave) process_chunk(c0);       // own chunk: wave 0, t=0
    ++t;
    for (int d = 1; d < CH; ++d) {
        const int cp = c0 + d;
        if (cp < CH) { if ((t & 7) == wave) process_chunk(cp); ++t; }
        const int cm = c0 - d;
        if (cm >= 0) { if ((t & 7) == wave) process_chunk(cm); ++t; }
    }

    // ---- final merge (wave 0): 6 bitonic merges + set-only last ----------
    __syncthreads();
#pragma unroll
    for (int s = 0; s < KNN; ++s)
        smerge[(wave * KNN + s) * 64 + lane] = keys[s];
    __syncthreads();
    float* mk = (float*)cbuf;                     // 16*64 floats, cbuf dead
    if (wave == 0) {
        float mm[KNN];
#pragma unroll
        for (int s = 0; s < KNN; ++s) mm[s] = smerge[s * 64 + lane];
#pragma unroll
        for (int w = 1; w < WPB; ++w) {
            float o[KNN];
#pragma unroll
            for (int s = 0; s < KNN; ++s)
                o[s] = smerge[(w * KNN + s) * 64 + lane];
            if (w < WPB - 1) {
                merge16(mm, o);
            } else {                              // set only, no sort needed
#pragma unroll
                for (int s = 0; s < KNN; ++s)
                    mm[s] = fminf(mm[s], o[KNN - 1 - s]);
            }
        }
#pragma unroll
        for (int s = 0; s < KNN; ++s) mk[s * 64 + lane] = mm[s];
    }
    __syncthreads();

    // ---- distributed tail: wave w finalizes slots (w, w+8) ----------------
    const int sA = wave, sB = wave + 8;
    const float kA = mk[sA * 64 + lane];
    const float kB = mk[sB * 64 + lane];
    const int jA = (int)(__float_as_uint(kA) & 0x1FFFu);   // local sorted idx
    const int jB = (int)(__float_as_uint(kB) & 0x1FFFu);

    const float4 a4 = sb[jA];
    const float4 b4 = sb[jB];
    const float dotA = qx * a4.x + qy * a4.y + qz * a4.z;
    const float dotB = qx * b4.x + qy * b4.y + qz * b4.z;
    float dA = (d2q + (a4.x * a4.x + a4.y * a4.y + a4.z * a4.z)) - (dotA + dotA);
    float dB = (d2q + (b4.x * b4.x + b4.y * b4.y + b4.z * b4.z)) - (dotB + dotB);
    dA = fmaxf(dA, 0.0f);
    dB = fmaxf(dB, 0.0f);

    smerge[wave * 64 + lane] = fminf(dA, dB);
    __syncthreads();
    float d1 = smerge[lane];
#pragma unroll
    for (int w = 1; w < WPB; ++w) d1 = fminf(d1, smerge[w * 64 + lane]);

    const float s0v  = d1 * 8.0f;                 // 2 * FILTER_SCALE^2 = 8
    const float sden = (s0v < EPSV) ? EPSV : s0v; // _eps_denom
    const float wA = fmaxf(1.0f - dA / sden, 0.0f);
    const float wB = fmaxf(1.0f - dB / sden, 0.0f);
    const float phA = (wA * wA) * (wA * wA);
    const float phB = (wB * wB) * (wB * wB);

    // map back to ORIGINAL indices through the sort permutation
    const int q_out = (b << 13) + perm[g * 64 + lane];
    const int joA = perm[(b << 13) + jA];
    const int joB = perm[(b << 13) + jB];

    out_idx [q_out * KNN + sA] = joA;  out_idx [q_out * KNN + sB] = joB;
    out_dist[q_out * KNN + sA] = dA;   out_dist[q_out * KNN + sB] = dB;
    out_phi [q_out * KNN + sA] = phA;  out_phi [q_out * KNN + sB] = phB;

    const float* bn = normals + (size_t)b * PP * 3;
    const float nax = bn[joA * 3 + 0], nay = bn[joA * 3 + 1], naz = bn[joA * 3 + 2];
    const float nbx = bn[joB * 3 + 0], nby = bn[joB * 3 + 1], nbz = bn[joB * 3 + 2];
    const float px = phA * nax + phB * nbx;
    const float py = phA * nay + phB * nby;
    const float pz = phA * naz + phB * nbz;
    const float ps = phA + phB;

    __syncthreads();                              // d1 reads done; reuse smerge
    smerge[(wave * 4 + 0) * 64 + lane] = px;
    smerge[(wave * 4 + 1) * 64 + lane] = py;
    smerge[(wave * 4 + 2) * 64 + lane] = pz;
    smerge[(wave * 4 + 3) * 64 + lane] = ps;
    __syncthreads();
    if (wave == 0) {
        float sx = 0.f, sy = 0.f, sz = 0.f, ss = 0.f;
#pragma unroll
        for (int w = 0; w < WPB; ++w) {
            sx += smerge[(w * 4 + 0) * 64 + lane];
            sy += smerge[(w * 4 + 1) * 64 + lane];
            sz += smerge[(w * 4 + 2) * 64 + lane];
            ss += smerge[(w * 4 + 3) * 64 + lane];
        }
        const float den = (ss < EPSV) ? EPSV : ss;
        out_n1[q_out * 3 + 0] = sx / den;
        out_n1[q_out * 3 + 1] = sy / den;
        out_n1[q_out * 3 + 2] = sz / den;
    }
}

// ---- K3: normal_w + second denoise (n2) -------------------------------------
__global__ void denoise2_kernel(const int* __restrict__ idx,
                                const float* __restrict__ phi,
                                const float* __restrict__ n1,
                                float* __restrict__ nw_out,
                                float* __restrict__ n2_out) {
    const int q = blockIdx.x * blockDim.x + threadIdx.x;
    if (q >= NPTS) return;
    const int b = q >> 13;
    const int gbase = b * PP;
    const float INV_SIG = 1.0f / (0.75f * 0.75f);

    const float ax = n1[q * 3 + 0];
    const float ay = n1[q * 3 + 1];
    const float az = n1[q * 3 + 2];
    const float an = fmaxf(sqrtf(ax * ax + ay * ay + az * az), 1e-12f);
    const float rx = ax / an, ry = ay / an, rz = az / an;

    float swn = 0.f, ox = 0.f, oy = 0.f, oz = 0.f;
#pragma unroll
    for (int s = 0; s < KNN; ++s) {
        const int j = idx[q * KNN + s];
        const float bx = n1[(gbase + j) * 3 + 0];
        const float by = n1[(gbase + j) * 3 + 1];
        const float bz = n1[(gbase + j) * 3 + 2];
        const float bnn = fmaxf(sqrtf(bx * bx + by * by + bz * bz), 1e-12f);
        const float ux = bx / bnn - rx;
        const float uy = by / bnn - ry;
        const float uz = bz / bnn - rz;
        const float dd = ux * ux + uy * uy + uz * uz;
        const float nw = expf(-dd * INV_SIG);
        nw_out[q * KNN + s] = nw;
        const float wk = phi[q * KNN + s] * nw;
        ox += wk * bx;                 // raw n1 (unnormalized), per reference
        oy += wk * by;
        oz += wk * bz;
        swn += wk;
    }
    const float den = (swn < EPSV) ? EPSV : swn;
    n2_out[q * 3 + 0] = ox / den;
    n2_out[q * 3 + 1] = oy / den;
    n2_out[q * 3 + 2] = oz / den;
}

// ---- K4: weights_proj + point-to-plane loss, per-block partial sums ---------
__global__ void loss_kernel(const float* __restrict__ pts,
                            const int* __restrict__ idx,
                            const float* __restrict__ dist,
                            const float* __restrict__ phi,
                            const float* __restrict__ nw,
                            const float* __restrict__ n2,
                            float* __restrict__ partial) {
    const int q = blockIdx.x * 64 + threadIdx.x;   // block = 64 (one wave)
    const int b = q >> 13;
    const int il = q & (PP - 1);
    const float* bp = pts + (size_t)b * PP * 3;
    const int gbase = b * PP;

    const float px = bp[il * 3 + 0];
    const float py = bp[il * 3 + 1];
    const float pz = bp[il * 3 + 2];

    float d[KNN];
#pragma unroll
    for (int s = 0; s < KNN; ++s) d[s] = dist[q * KNN + s];
    float d1 = d[0];
#pragma unroll
    for (int s = 1; s < KNN; ++s) d1 = fminf(d1, d[s]);
    const float thresh = 4.0f * d1;                // FILTER_SCALE * d1 * 2

    float num = 0.f, den = 0.f;
#pragma unroll
    for (int s = 0; s < KNN; ++s) {
        float w = phi[q * KNN + s] * nw[q * KNN + s];
        if (d[s] > thresh) w = 0.f;                // ball-query mask
        const int j = idx[q * KNN + s];
        const float nx = n2[(gbase + j) * 3 + 0];
        const float ny = n2[(gbase + j) * 3 + 1];
        const float nz = n2[(gbase + j) * 3 + 2];
        const float dts = (bp[j * 3 + 0] - px) * nx +
                          (bp[j * 3 + 1] - py) * ny +
                          (bp[j * 3 + 2] - pz) * nz;
        num += dts * dts * w;
        den += w;
    }
    const float dd = (den < EPSV) ? EPSV : den;
    float loss = num / dd;

#pragma unroll
    for (int off = 32; off >= 1; off >>= 1) loss += __shfl_down(loss, off, 64);
    if (threadIdx.x == 0) partial[blockIdx.x] = loss;
}

// ---- K5: final mean ---------------------------------------------------------
__global__ void finalize_kernel(const float* __restrict__ partial,
                                float* __restrict__ out) {
    float v = partial[threadIdx.x] + partial[threadIdx.x + 64] +
              partial[threadIdx.x + 128] + partial[threadIdx.x + 192];
#pragma unroll
    for (int off = 32; off >= 1; off >>= 1) v += __shfl_down(v, off, 64);
    if (threadIdx.x == 0) out[0] = v / (float)NPTS;
}

// ---- launch -----------------------------------------------------------------
extern "C" void kernel_launch(void* const* d_in, const int* in_sizes, int n_in,
                              void* d_out, int out_size, void* d_ws, size_t ws_size,
                              hipStream_t stream) {
    const float* points  = (const float*)d_in[0];   // (2, 8192, 3) f32
    const float* normals = (const float*)d_in[1];   // (2, 8192, 3) f32
    float* out = (float*)d_out;                     // scalar f32

    // workspace layout (floats): idx | dist | phi | {sort scratch / nw} | n1 | n2 | part
    float* wsf    = (float*)d_ws;
    int*   w_idx  = (int*)wsf;                      // 16384*16 ints
    float* w_dist = wsf + 262144;                   // 16384*16
    float* w_phi  = wsf + 524288;                   // 16384*16
    float* region = wsf + 786432;                   // 262144 floats
    //   sort scratch lives in `region`, dead once knn_sorted completes;
    //   denoise2 then reuses `region` as nw.
    float4* w_sorted4 = (float4*)region;            // 65536 floats
    int*    w_perm    = (int*)(region + 65536);     // 16384
    int*    w_hist    = (int*)(region + 81920);     // 8192
    int*    w_cursor  = (int*)(region + 90112);     // 8192
    float4* w_bbmin   = (float4*)(region + 98304);  // 1024 floats
    float4* w_bbmax   = (float4*)(region + 99328);  // 1024 floats
    float*  w_nw      = region;                     // reused after knn
    float* w_n1   = wsf + 1048576;                  // 16384*3
    float* w_n2   = wsf + 1097728;                  // 16384*3
    float* w_part = wsf + 1146880;                  // 256

    zero_kernel   <<<1, 1024, 0, stream>>>(w_hist);
    hist_kernel   <<<NPTS / 256, 256, 0, stream>>>(points, w_hist);
    scan_kernel   <<<NB, 1024, 0, stream>>>(w_hist, w_cursor);
    scatter_kernel<<<NPTS / 256, 256, 0, stream>>>(points, w_cursor, w_sorted4, w_perm);
    bbox_kernel   <<<32, 512, 0, stream>>>(w_sorted4, w_bbmin, w_bbmax);
    knn_sorted_kernel<<<NPTS / QPB, TPB, 0, stream>>>(
        w_sorted4, w_perm, normals, w_bbmin, w_bbmax,
        w_idx, w_dist, w_phi, w_n1);
    denoise2_kernel<<<NPTS / 64, 64, 0, stream>>>(w_idx, w_phi, w_n1, w_nw, w_n2);
    loss_kernel   <<<NPTS / 64, 64, 0, stream>>>(points, w_idx, w_dist, w_phi, w_nw, w_n2, w_part);
    finalize_kernel<<<1, 64, 0, stream>>>(w_part, out);
}